// Round 10
// baseline (256.502 us; speedup 1.0000x reference)
//
#include <hip/hip_runtime.h>
#include <hip/hip_bf16.h>
#include <cstdint>

#define B_ 256
#define T_ 600
#define D_ 256

typedef __attribute__((ext_vector_type(8))) short bf16x8;
typedef __attribute__((ext_vector_type(4))) float f32x4;

__device__ __forceinline__ float fast_sigmoid(float x) {
    return __fdividef(1.0f, 1.0f + __expf(-x));
}
__device__ __forceinline__ float fast_tanh(float x) {
    return 1.0f - __fdividef(2.0f, __expf(2.0f * x) + 1.0f);
}
__device__ __forceinline__ ushort f2bf(float f) {
    unsigned u = __float_as_uint(f);
    u += 0x7FFF + ((u >> 16) & 1);   // round-to-nearest-even
    return (ushort)(u >> 16);
}

// ---------------------------------------------------------------------------
// prenet (+ fused init_concat + Lw16 bf16 pre-pack by block 0)
// ---------------------------------------------------------------------------
__global__ __launch_bounds__(256) void prenet_kernel(
    const float* __restrict__ pre_in, const float* __restrict__ noise,
    const float* __restrict__ w1, const float* __restrict__ b1,
    const float* __restrict__ w2, const float* __restrict__ b2,
    const float* __restrict__ ctx_in, const float* __restrict__ spk,
    const float* __restrict__ L_w, ushort* __restrict__ Lw16,
    float* __restrict__ Xgru, float* __restrict__ Xrnn)
{
    __shared__ float xin[144];
    __shared__ float p1[256];
    int b = blockIdx.x, t = threadIdx.x;
    if (b == 0) {
#pragma unroll
        for (int i = 0; i < 32; ++i) {
            int idx = i * 256 + t;
            Lw16[idx] = f2bf(L_w[idx]);
        }
    }
    float s = spk[b * 256 + t];
    Xgru[b * 640 + t] = ctx_in[b * 256 + t];
    Xgru[b * 640 + 384 + t] = s;
    Xrnn[b * 832 + 512 + t] = s;
    if (t < 64) Xrnn[b * 832 + 768 + t] = noise[b * 64 + t];
    if (t < 80) xin[t] = pre_in[b * 80 + t];
    else if (t < 144) xin[t] = noise[b * 64 + (t - 80)];
    __syncthreads();
    float acc = b1[t];
    const float4* w = (const float4*)(w1 + t * 144);
    const float4* xi = (const float4*)xin;
#pragma unroll 9
    for (int k = 0; k < 36; ++k) {
        float4 wv = w[k]; float4 xv = xi[k];
        acc += wv.x * xv.x + wv.y * xv.y + wv.z * xv.z + wv.w * xv.w;
    }
    p1[t] = fmaxf(acc, 0.f);
    __syncthreads();
    if (t < 128) {
        float a2 = b2[t];
        const float4* w2v = (const float4*)(w2 + t * 256);
        const float4* pv = (const float4*)p1;
#pragma unroll 8
        for (int k = 0; k < 64; ++k) {
            float4 wv = w2v[k]; float4 xv = pv[k];
            a2 += wv.x * xv.x + wv.y * xv.y + wv.z * xv.z + wv.w * xv.w;
        }
        Xgru[b * 640 + 256 + t] = fmaxf(a2, 0.f);
    }
}

// ---------------------------------------------------------------------------
// gemm16: 16x64 tile, 256 threads, acc 1x4/thread, register-prefetch.
// ---------------------------------------------------------------------------
__global__ __launch_bounds__(256) void gemm16(
    const float* __restrict__ A1, int K1, const float* __restrict__ B1,
    const float* __restrict__ A2, int K2, const float* __restrict__ B2,
    const float* __restrict__ bias, float* __restrict__ C, int N)
{
    __shared__ float As[16][17];
    __shared__ float Bs[16][68];
    int tid = threadIdx.x;
    int m0 = blockIdx.x * 16, n0 = blockIdx.y * 64;
    int tm = tid >> 4, tn = tid & 15;
    int lr = tid >> 2, lq = tid & 3;
    int ar = tid >> 2;
    float acc[4] = {};
    int nkt = (K1 + K2) >> 4;

    float4 av, bv;
    {
        const float* A; const float* Bb; int kk; int K;
        if (0 < K1) { A = A1; Bb = B1; kk = 0; K = K1; }
        else        { A = A2; Bb = B2; kk = -K1; K = K2; }
        if (tid < 64) av = *(const float4*)&A[(size_t)(m0 + ar) * K + kk + lq * 4];
        bv = *(const float4*)&Bb[(size_t)(n0 + lr) * K + kk + lq * 4];
    }
    for (int kt = 0; kt < nkt; ++kt) {
        __syncthreads();
        if (tid < 64) {
            As[lq * 4 + 0][ar] = av.x; As[lq * 4 + 1][ar] = av.y;
            As[lq * 4 + 2][ar] = av.z; As[lq * 4 + 3][ar] = av.w;
        }
        Bs[lq * 4 + 0][lr] = bv.x; Bs[lq * 4 + 1][lr] = bv.y;
        Bs[lq * 4 + 2][lr] = bv.z; Bs[lq * 4 + 3][lr] = bv.w;
        __syncthreads();
        if (kt + 1 < nkt) {
            int kg = (kt + 1) << 4;
            const float* A; const float* Bb; int kk; int K;
            if (kg < K1) { A = A1; Bb = B1; kk = kg; K = K1; }
            else         { A = A2; Bb = B2; kk = kg - K1; K = K2; }
            if (tid < 64) av = *(const float4*)&A[(size_t)(m0 + ar) * K + kk + lq * 4];
            bv = *(const float4*)&Bb[(size_t)(n0 + lr) * K + kk + lq * 4];
        }
#pragma unroll
        for (int k = 0; k < 16; ++k) {
            float a = As[k][tm];
            float4 b4 = *(const float4*)&Bs[k][tn * 4];
            acc[0] = fmaf(a, b4.x, acc[0]);
            acc[1] = fmaf(a, b4.y, acc[1]);
            acc[2] = fmaf(a, b4.z, acc[2]);
            acc[3] = fmaf(a, b4.w, acc[3]);
        }
    }
    float4 bb = make_float4(0.f, 0.f, 0.f, 0.f);
    if (bias) bb = *(const float4*)&bias[n0 + tn * 4];
    float4 o = make_float4(acc[0] + bb.x, acc[1] + bb.y, acc[2] + bb.z, acc[3] + bb.w);
    *(float4*)&C[(size_t)(m0 + tm) * N + n0 + tn * 4] = o;
}

// ---------------------------------------------------------------------------
// gru_combine
// ---------------------------------------------------------------------------
__global__ __launch_bounds__(256) void gru_combine(
    const float* __restrict__ Cgi, const float* __restrict__ Cgh,
    const float* __restrict__ h_in, float* __restrict__ ah_out,
    float* __restrict__ Xrnn)
{
    int b = blockIdx.x, j = threadIdx.x;
    float gir = Cgi[b * 768 + j], giz = Cgi[b * 768 + 256 + j], gin = Cgi[b * 768 + 512 + j];
    float ghr = Cgh[b * 768 + j], ghz = Cgh[b * 768 + 256 + j], ghn = Cgh[b * 768 + 512 + j];
    float rr = fast_sigmoid(gir + ghr);
    float zz = fast_sigmoid(giz + ghz);
    float nn = fast_tanh(gin + rr * ghn);
    float h = (1.f - zz) * nn + zz * h_in[b * 256 + j];
    ah_out[b * 256 + j] = h;
    Xrnn[b * 832 + 256 + j] = h;
}

// ---------------------------------------------------------------------------
// attn_u v8: chunked double-buffered prefetch (gemm-style). dt in 4 chunks
// of 4; ping-pong regs afP/evP <-> afQ/evQ (all static indices); afr read
// from global Lw16 (L2-hot), no lwS. locs padded [64][40] (80B rows, 16B-
// aligned). 256 threads = 4 waves x 16 t; grid (10, B).
// ---------------------------------------------------------------------------
#define TCH 64
__global__ __launch_bounds__(256) void attn_u_kernel(
    const float* __restrict__ esp, const float* __restrict__ pq,
    const float* __restrict__ cum, const float* __restrict__ prv,
    const float* __restrict__ conv_w, const ushort* __restrict__ Lw16,
    const float* __restrict__ L_b, const float* __restrict__ v_w,
    float* __restrict__ u)
{
    __shared__ float cumL[TCH + 32], prvL[TCH + 32];
    __shared__ float cwL[32 * 62];
    __shared__ ushort locs[TCH][40];      // padded: bank-spread + 16B-aligned rows
    __shared__ float pq2s[256], vvs[256];
    int b = blockIdx.y;
    int t0 = blockIdx.x * TCH;
    int tid = threadIdx.x;
    int lane = tid & 63, wv = tid >> 6;
    int cl = lane & 15, gr = lane >> 4;

    int tw = t0 + wv * 16 + cl;
    int tc = (tw < T_) ? tw : (T_ - 1);
    const float4* ep4 = (const float4*)(esp + ((size_t)b * T_ + tc) * 256) + gr;
    const bf16x8* lwp = (const bf16x8*)Lw16;   // frag(dt) = lwp[(dt*16+cl)*4+gr]

    // prologue: chunk 0 in flight during staging + conv
    bf16x8 afP[4], afQ[4];
    float4 evP[4], evQ[4];
#pragma unroll
    for (int j = 0; j < 4; ++j) { afP[j] = lwp[(j * 16 + cl) * 4 + gr]; evP[j] = ep4[j * 4]; }

    // ---- staging
    for (int i = tid; i < TCH + 30; i += 256) {
        int tg = t0 + i - 15;
        bool ok = (tg >= 0) && (tg < T_);
        cumL[i] = ok ? cum[b * T_ + tg] : 0.f;
        prvL[i] = ok ? prv[b * T_ + tg] : 0.f;
    }
    for (int i = tid; i < 32 * 62; i += 256) cwL[i] = conv_w[i];
    pq2s[tid] = pq[b * 256 + tid] + L_b[tid];
    vvs[tid] = v_w[tid];
    __syncthreads();

    // ---- conv (LDS stencil; cumL/prvL reads are 32-lane broadcasts)
    {
        int f = tid & 31, ts = tid >> 5;
        const float* c0 = &cwL[f * 62];
        float acc[8] = {};
#pragma unroll
        for (int k = 0; k < 31; ++k) {
            float wcv = c0[k], wpv = c0[31 + k];
#pragma unroll
            for (int i = 0; i < 8; ++i)
                acc[i] = fmaf(cumL[ts * 8 + i + k], wcv, fmaf(prvL[ts * 8 + i + k], wpv, acc[i]));
        }
#pragma unroll
        for (int i = 0; i < 8; ++i)
            locs[ts * 8 + i][f] = f2bf(acc[i]);
    }
    __syncthreads();

    bf16x8 locf = *(const bf16x8*)&locs[wv * 16 + cl][gr * 8];
    float sum = 0.f;

#define CHUNK(AF, EV, BASE)                                                      \
    do {                                                                         \
        _Pragma("unroll")                                                        \
        for (int j = 0; j < 4; ++j) {                                            \
            int dt = (BASE) + j;                                                 \
            float4 pq4 = *(const float4*)&pq2s[dt * 16 + gr * 4];                \
            float4 vv4 = *(const float4*)&vvs[dt * 16 + gr * 4];                 \
            f32x4 acc = {pq4.x, pq4.y, pq4.z, pq4.w};                            \
            acc = __builtin_amdgcn_mfma_f32_16x16x32_bf16(AF[j], locf, acc, 0, 0, 0); \
            sum = fmaf(fast_tanh(EV[j].x + acc[0]), vv4.x, sum);                 \
            sum = fmaf(fast_tanh(EV[j].y + acc[1]), vv4.y, sum);                 \
            sum = fmaf(fast_tanh(EV[j].z + acc[2]), vv4.z, sum);                 \
            sum = fmaf(fast_tanh(EV[j].w + acc[3]), vv4.w, sum);                 \
        }                                                                        \
    } while (0)

#pragma unroll
    for (int j = 0; j < 4; ++j) { afQ[j] = lwp[((4 + j) * 16 + cl) * 4 + gr]; evQ[j] = ep4[(4 + j) * 4]; }
    CHUNK(afP, evP, 0);
#pragma unroll
    for (int j = 0; j < 4; ++j) { afP[j] = lwp[((8 + j) * 16 + cl) * 4 + gr]; evP[j] = ep4[(8 + j) * 4]; }
    CHUNK(afQ, evQ, 4);
#pragma unroll
    for (int j = 0; j < 4; ++j) { afQ[j] = lwp[((12 + j) * 16 + cl) * 4 + gr]; evQ[j] = ep4[(12 + j) * 4]; }
    CHUNK(afP, evP, 8);
    CHUNK(afQ, evQ, 12);
#undef CHUNK

    sum += __shfl_xor(sum, 16, 64);
    sum += __shfl_xor(sum, 32, 64);
    if (lane < 16 && tw < T_) u[b * T_ + tw] = sum;
}

// ---------------------------------------------------------------------------
// softmax + context (round-8 version: simple, correct)
// ---------------------------------------------------------------------------
__global__ __launch_bounds__(1024) void softmax_ctx_kernel(
    const float* __restrict__ u, const int* __restrict__ plen,
    const float* __restrict__ enc,
    float* __restrict__ scores, float* __restrict__ ctx_out,
    float* __restrict__ Xrnn)
{
    __shared__ float sc[T_];
    __shared__ float red[16];
    __shared__ float part[16][256];
    int b = blockIdx.x, tid = threadIdx.x;
    int lane = tid & 63, wid = tid >> 6;
    int pl = plen[b];
    float mv = -1e30f;
    if (tid < T_) {
        float uv = u[b * T_ + tid];
        mv = (tid < pl) ? uv : -1e9f;
        sc[tid] = mv;
    }
    float m = mv;
#pragma unroll
    for (int off = 32; off > 0; off >>= 1) m = fmaxf(m, __shfl_xor(m, off, 64));
    if (lane == 0) red[wid] = m;
    __syncthreads();
    m = red[0];
#pragma unroll
    for (int i = 1; i < 16; ++i) m = fmaxf(m, red[i]);
    float ev = 0.f;
    if (tid < T_) ev = __expf(sc[tid] - m);
    float s = ev;
    __syncthreads();
#pragma unroll
    for (int off = 32; off > 0; off >>= 1) s += __shfl_xor(s, off, 64);
    if (lane == 0) red[wid] = s;
    __syncthreads();
    float tot = 0.f;
#pragma unroll
    for (int i = 0; i < 16; ++i) tot += red[i];
    float inv = __fdividef(1.0f, tot);
    if (tid < T_) {
        float scv = ev * inv;
        scores[b * T_ + tid] = scv;
        sc[tid] = scv;
    }
    __syncthreads();
    float a0 = 0.f, a1 = 0.f, a2 = 0.f, a3 = 0.f;
    const float4* ep = (const float4*)(enc + ((size_t)b * T_ + wid) * 256) + lane;
    for (int t = wid; t < T_; t += 16) {
        float sv = sc[t];
        float4 ev4 = *ep;
        a0 = fmaf(sv, ev4.x, a0);
        a1 = fmaf(sv, ev4.y, a1);
        a2 = fmaf(sv, ev4.z, a2);
        a3 = fmaf(sv, ev4.w, a3);
        ep += 16 * 64;
    }
    part[wid][lane * 4 + 0] = a0;
    part[wid][lane * 4 + 1] = a1;
    part[wid][lane * 4 + 2] = a2;
    part[wid][lane * 4 + 3] = a3;
    __syncthreads();
    if (tid < 256) {
        float c = 0.f;
#pragma unroll
        for (int q = 0; q < 16; ++q) c += part[q][tid];
        ctx_out[b * 256 + tid] = c;
        Xrnn[b * 832 + tid] = c;
    }
}

// ---------------------------------------------------------------------------
// lstm_combine
// ---------------------------------------------------------------------------
__global__ __launch_bounds__(512) void lstm_combine(
    const float* __restrict__ G, const float* __restrict__ bih,
    const float* __restrict__ bhh, const float* __restrict__ c_in,
    const float* __restrict__ x_in, float* __restrict__ h_out,
    float* __restrict__ c_out, float* __restrict__ x_next)
{
    int b = blockIdx.x, j = threadIdx.x;
    size_t base = (size_t)b * 2048;
    float gi = G[base + j] + bih[j] + bhh[j];
    float gf = G[base + 512 + j] + bih[512 + j] + bhh[512 + j];
    float gg = G[base + 1024 + j] + bih[1024 + j] + bhh[1024 + j];
    float go = G[base + 1536 + j] + bih[1536 + j] + bhh[1536 + j];
    float c = fast_sigmoid(gf) * c_in[b * 512 + j] + fast_sigmoid(gi) * fast_tanh(gg);
    float h = fast_sigmoid(go) * fast_tanh(c);
    h_out[b * 512 + j] = h;
    c_out[b * 512 + j] = c;
    x_next[b * 512 + j] = x_in[b * 512 + j] + h;
}

// ---------------------------------------------------------------------------
// mel
// ---------------------------------------------------------------------------
__global__ __launch_bounds__(256) void mel_kernel(
    const float* __restrict__ x2, const float* __restrict__ mel_w,
    int r, float* __restrict__ mels)
{
    __shared__ float xl[512];
    int b = blockIdx.x, tid = threadIdx.x;
    xl[tid] = x2[b * 512 + tid];
    xl[256 + tid] = x2[b * 512 + 256 + tid];
    __syncthreads();
    for (int idx = tid; idx < 80 * r; idx += 256) {
        int mrow = (idx / r) * 10 + (idx % r);
        const float4* w = (const float4*)(mel_w + (size_t)mrow * 512);
        const float4* xv = (const float4*)xl;
        float acc = 0.f;
#pragma unroll 16
        for (int k = 0; k < 128; ++k) {
            float4 a = w[k], c = xv[k];
            acc += a.x * c.x + a.y * c.y + a.z * c.z + a.w * c.w;
        }
        mels[(size_t)b * 80 * r + idx] = acc;
    }
}

// ---------------------------------------------------------------------------
extern "C" void kernel_launch(void* const* d_in, const int* in_sizes, int n_in,
                              void* d_out, int out_size, void* d_ws, size_t ws_size,
                              hipStream_t stream)
{
    const float* enc    = (const float*)d_in[0];
    const float* esp    = (const float*)d_in[1];
    const float* pre_in = (const float*)d_in[2];
    const float* ah_in  = (const float*)d_in[3];
    const float* h1_in  = (const float*)d_in[4];
    const float* h2_in  = (const float*)d_in[5];
    const float* c1_in  = (const float*)d_in[6];
    const float* c2_in  = (const float*)d_in[7];
    const float* ctx_in = (const float*)d_in[8];
    const float* spk    = (const float*)d_in[9];
    const float* noise  = (const float*)d_in[10];
    const float* cum    = (const float*)d_in[11];
    const float* prv    = (const float*)d_in[12];
    const int*   plen   = (const int*)d_in[13];
    const float* fc1_w  = (const float*)d_in[14];
    const float* fc1_b  = (const float*)d_in[15];
    const float* fc2_w  = (const float*)d_in[16];
    const float* fc2_b  = (const float*)d_in[17];
    const float* conv_w = (const float*)d_in[18];
    const float* L_w    = (const float*)d_in[19];
    const float* L_b    = (const float*)d_in[20];
    const float* W_w    = (const float*)d_in[21];
    const float* W_b    = (const float*)d_in[22];
    const float* v_w    = (const float*)d_in[23];
    const float* g_wih  = (const float*)d_in[24];
    const float* g_whh  = (const float*)d_in[25];
    const float* g_bih  = (const float*)d_in[26];
    const float* g_bhh  = (const float*)d_in[27];
    const float* ri_w   = (const float*)d_in[28];
    const float* ri_b   = (const float*)d_in[29];
    const float* l1_wih = (const float*)d_in[30];
    const float* l1_whh = (const float*)d_in[31];
    const float* l1_bih = (const float*)d_in[32];
    const float* l1_bhh = (const float*)d_in[33];
    const float* l2_wih = (const float*)d_in[34];
    const float* l2_whh = (const float*)d_in[35];
    const float* l2_bih = (const float*)d_in[36];
    const float* l2_bhh = (const float*)d_in[37];
    const float* mel_w  = (const float*)d_in[38];

    int r = (out_size - 808960) / 20480;
    if (r < 1) r = 1;
    if (r > 10) r = 10;

    float* out    = (float*)d_out;
    float* mels   = out;
    float* scores = out + (size_t)20480 * r;
    float* ah_out = scores + 153600;
    float* h1_out = ah_out + 65536;
    float* h2_out = h1_out + 131072;
    float* c1_out = h2_out + 131072;
    float* c2_out = c1_out + 131072;
    float* ctx_out = c2_out + 131072;

    float* ws   = (float*)d_ws;
    float* Xgru = ws;                    // 256*640
    float* Cgi  = Xgru + 163840;         // 256*768
    float* Cgh  = Cgi + 196608;
    float* pq   = Cgh + 196608;          // 256*256
    float* uu   = pq + 65536;            // 256*600
    float* Xrnn = uu + 153600;           // 256*832
    float* x0   = Xrnn + 212992;         // 256*512
    float* x1   = x0 + 131072;
    float* x2   = x1 + 131072;
    float* G    = x2 + 131072;           // 256*2048
    ushort* Lw16 = (ushort*)(G + 524288); // 256*32 bf16 = 16 KB

    prenet_kernel<<<256, 256, 0, stream>>>(pre_in, noise, fc1_w, fc1_b, fc2_w, fc2_b,
                                           ctx_in, spk, L_w, Lw16, Xgru, Xrnn);
    gemm16<<<dim3(16, 12), 256, 0, stream>>>(Xgru, 640, g_wih, nullptr, 0, nullptr, g_bih, Cgi, 768);
    gemm16<<<dim3(16, 12), 256, 0, stream>>>(ah_in, 256, g_whh, nullptr, 0, nullptr, g_bhh, Cgh, 768);
    gru_combine<<<256, 256, 0, stream>>>(Cgi, Cgh, ah_in, ah_out, Xrnn);
    gemm16<<<dim3(16, 4), 256, 0, stream>>>(ah_out, 256, W_w, nullptr, 0, nullptr, W_b, pq, 256);
    attn_u_kernel<<<dim3(10, 256), 256, 0, stream>>>(esp, pq, cum, prv, conv_w, Lw16, L_b, v_w, uu);
    softmax_ctx_kernel<<<256, 1024, 0, stream>>>(uu, plen, enc, scores, ctx_out, Xrnn);
    gemm16<<<dim3(16, 8), 256, 0, stream>>>(Xrnn, 832, ri_w, nullptr, 0, nullptr, ri_b, x0, 512);
    gemm16<<<dim3(16, 32), 256, 0, stream>>>(x0, 512, l1_wih, h1_in, 512, l1_whh, nullptr, G, 2048);
    lstm_combine<<<256, 512, 0, stream>>>(G, l1_bih, l1_bhh, c1_in, x0, h1_out, c1_out, x1);
    gemm16<<<dim3(16, 32), 256, 0, stream>>>(x1, 512, l2_wih, h2_in, 512, l2_whh, nullptr, G, 2048);
    lstm_combine<<<256, 512, 0, stream>>>(G, l2_bih, l2_bhh, c2_in, x1, h2_out, c2_out, x2);
    mel_kernel<<<256, 256, 0, stream>>>(x2, mel_w, r, mels);
}